// Round 17
// baseline (130.878 us; speedup 1.0000x reference)
//
#include <hip/hip_runtime.h>
#include <hip/hip_bf16.h>

#define H 500
#define D_IN 512
#define D_OUT 100
#define STEPS 49
#define NWG 4
#define NBLK2 48
#define SPINL 240
#define SENT 0xFFFFFFFFu

typedef _Float16 h2_t __attribute__((ext_vector_type(2)));

#if defined(__has_builtin)
#if __has_builtin(__builtin_amdgcn_fdot2)
#define HAVE_FDOT2 1
#endif
#endif

__device__ __forceinline__ float fdot2f(h2_t a, h2_t b, float c) {
#ifdef HAVE_FDOT2
    return __builtin_amdgcn_fdot2(a, b, c, false);
#else
    return c + (float)a[0] * (float)b[0] + (float)a[1] * (float)b[1];
#endif
}
__device__ __forceinline__ h2_t bch2(unsigned u) { return __builtin_bit_cast(h2_t, u); }
__device__ __forceinline__ unsigned pk(float a, float b) {
    return __builtin_bit_cast(unsigned, h2_t{(_Float16)a, (_Float16)b});
}
__device__ __forceinline__ float tanh_fast(float x) {
    const float e = __expf(2.f * x);
    return 1.f - 2.f / (e + 1.f);
}
__device__ __forceinline__ int clen(int g) { return (g < 3) ? 128 : (H - 384); }  // 116
__device__ __forceinline__ unsigned aload(const float* p) {
    return __builtin_bit_cast(unsigned,
        __hip_atomic_load(p, __ATOMIC_RELAXED, __HIP_MEMORY_SCOPE_AGENT));
}
__device__ __forceinline__ void astore(float* p, float v) {
    __hip_atomic_store(p, v, __ATOMIC_RELAXED, __HIP_MEMORY_SCOPE_AGENT);
}
// XCD-L2 fast path: sc0 load bypasses L1, reads the XCD's shared L2.
__device__ __forceinline__ void l2load3(const float* p1, const float* p2, const float* p3,
                                        unsigned& a, unsigned& b, unsigned& c) {
    asm volatile("global_load_dword %0, %3, off sc0\n\t"
                 "global_load_dword %1, %4, off sc0\n\t"
                 "global_load_dword %2, %5, off sc0\n\t"
                 "s_waitcnt vmcnt(0)"
                 : "=&v"(a), "=&v"(b), "=&v"(c)
                 : "v"(p1), "v"(p2), "v"(p3));
}

// ---------------- K1: xproj + sentinel-init of part + elect clear.
__global__ void __launch_bounds__(512, 1)
k1_xproj(const float* __restrict__ x, const float* __restrict__ W_ih,
         const float* __restrict__ b_ih, const float* __restrict__ b_hh,
         float* __restrict__ xproj, float* __restrict__ part, unsigned* __restrict__ elect) {
    if (blockIdx.x >= 63) {
        const int b = blockIdx.x - 63;                 // 0..24
        if (b == 0 && threadIdx.x < 16) elect[threadIdx.x] = 0u;
        float4* p4 = (float4*)part;
        const float4 s4 = {__builtin_bit_cast(float, SENT), __builtin_bit_cast(float, SENT),
                           __builtin_bit_cast(float, SENT), __builtin_bit_cast(float, SENT)};
        const int i0 = b * 1024 + threadIdx.x;
        const int i1 = i0 + 512;
        if (i0 < 25088) p4[i0] = s4;
        if (i1 < 25088) p4[i1] = s4;
        return;
    }
    __shared__ float xl[D_IN * STEPS];                 // 100352 B
    const int tid = threadIdx.x;
    for (int i = tid; i < D_IN * STEPS; i += 512) xl[i] = x[i];
    __syncthreads();

    const int wv = tid >> 6, lane = tid & 63;
    const int r = blockIdx.x * 8 + wv;                 // 0..503
    if (r >= H) return;
    float wr8[8];
#pragma unroll
    for (int k = 0; k < 8; k++) wr8[k] = W_ih[r * D_IN + k * 64 + lane];
    float p[STEPS];
#pragma unroll
    for (int t = 0; t < STEPS; t++) p[t] = 0.f;
#pragma unroll
    for (int k = 0; k < 8; k++) {
        const float* xr = xl + (k * 64 + lane) * STEPS;
#pragma unroll
        for (int t = 0; t < STEPS; t++) p[t] = fmaf(wr8[k], xr[t], p[t]);
    }
#pragma unroll
    for (int t = 0; t < STEPS; t++) {
        float v = p[t];
        v += __shfl_xor(v, 32); v += __shfl_xor(v, 16); v += __shfl_xor(v, 8);
        v += __shfl_xor(v, 4);  v += __shfl_xor(v, 2);  v += __shfl_xor(v, 1);
        p[t] = v;
    }
    if (lane == 0) {
        const float b = b_ih[r] + b_hh[r];
        for (int t = 0; t < STEPS; t++) xproj[t * 512 + r] = p[t] + b;
    }
}

// ---------------- K2: column-split scan with same-XCD election + L2 exchange.
// 48 blocks; per-XCD tickets in elect[0..7]; 4th block on an XCD claims elect[8];
// tickets 0..3 of winning XCD = workers g=ticket (4 CUs, ONE shared L2); rest exit.
// Exchange: writers dual-store partials (plain -> local L2 dirty; +sc1 -> MALL,
// same addr/value). Readers poll with sc0 loads (L2 fast path); after SPINL
// failed spins latch per-thread to agent polling (r11-proven, no hang).
__global__ void __launch_bounds__(512, 1)
k2_scan(const float* __restrict__ hidden0, const float* __restrict__ W_hh,
        const float* __restrict__ xproj, float* part, float* __restrict__ Hs,
        unsigned* elect) {
    __shared__ uint4 wl[16 * 512];                  // 131072 B
    __shared__ __align__(16) _Float16 hch[2][128];  // 512 B
    __shared__ unsigned role_s[2];

    const int tid = threadIdx.x;

    if (tid == 0) {
        unsigned xcd;
        asm volatile("s_getreg_b32 %0, hwreg(HW_REG_XCC_ID)" : "=s"(xcd));
        xcd &= 7u;
        const unsigned ticket = __hip_atomic_fetch_add(&elect[xcd], 1u,
                                    __ATOMIC_RELAXED, __HIP_MEMORY_SCOPE_AGENT);
        if (ticket == 3u) {
            unsigned exp0 = 0u;
            __hip_atomic_compare_exchange_strong(&elect[8], &exp0, xcd + 1u,
                __ATOMIC_RELAXED, __ATOMIC_RELAXED, __HIP_MEMORY_SCOPE_AGENT);
        }
        unsigned win;
        do {
            win = __hip_atomic_load(&elect[8], __ATOMIC_RELAXED, __HIP_MEMORY_SCOPE_AGENT);
        } while (win == 0u);
        role_s[0] = (win == xcd + 1u && ticket < 4u) ? 1u : 0u;
        role_s[1] = ticket;
    }
    __syncthreads();
    if (role_s[0] == 0u) return;
    const int g = (int)role_s[1];                   // 0..3

    const int rr = tid >> 2, sub = tid & 3;
    const int myLen = clen(g);

    // preamble: W_hh[:, 128g + 32sub .. +32), rows 128d+rr -> LDS f16
#pragma unroll
    for (int d = 0; d < 4; d++) {
        uint4 u[4] = {{0,0,0,0},{0,0,0,0},{0,0,0,0},{0,0,0,0}};
        if (rr < clen(d)) {
            const int row = 128 * d + rr;
            const float* rowp = W_hh + (size_t)row * H + 128 * g + 32 * sub;
            const int cmax = myLen - 32 * sub;
            if (cmax >= 32) {
#pragma unroll
                for (int q8 = 0; q8 < 4; q8++) {
                    const float4 f0 = *(const float4*)(rowp + 8 * q8);
                    const float4 f1 = *(const float4*)(rowp + 8 * q8 + 4);
                    u[q8].x = pk(f0.x, f0.y); u[q8].y = pk(f0.z, f0.w);
                    u[q8].z = pk(f1.x, f1.y); u[q8].w = pk(f1.z, f1.w);
                }
            } else {
                float f[32];
#pragma unroll
                for (int cc = 0; cc < 32; cc++) f[cc] = (cc < cmax) ? rowp[cc] : 0.f;
#pragma unroll
                for (int q8 = 0; q8 < 4; q8++) {
                    u[q8].x = pk(f[8*q8+0], f[8*q8+1]);
                    u[q8].y = pk(f[8*q8+2], f[8*q8+3]);
                    u[q8].z = pk(f[8*q8+4], f[8*q8+5]);
                    u[q8].w = pk(f[8*q8+6], f[8*q8+7]);
                }
            }
        }
#pragma unroll
        for (int c = 0; c < 4; c++) wl[(d * 4 + c) * 512 + tid] = u[c];
    }
    if (tid < 128) hch[0][tid] = (tid < myLen) ? (_Float16)hidden0[128 * g + tid]
                                               : (_Float16)0.f;
    else if (tid < 256) hch[1][tid - 128] = (_Float16)0.f;
    __syncthreads();

    bool fb = false;                                // latched fallback (per thread)
#pragma unroll 1
    for (int t = 0; t < STEPS; ++t) {
        const int cur = t & 1;
        float xp = 0.f;
        if (sub == 0 && rr < myLen) xp = xproj[t * 512 + 128 * g + rr];  // plain (complete)

        const uint4* hc = (const uint4*)&hch[cur][0];
        uint4 hv4[4];
#pragma unroll
        for (int c = 0; c < 4; c++) hv4[c] = hc[sub * 4 + c];   // broadcast reads

        float own = 0.f;
#pragma unroll
        for (int k = 0; k < 4; k++) {
            const int d = (g + 1 + k) & 3;          // k=0..2 remote, k=3 own
            float s = 0.f;
#pragma unroll
            for (int c = 0; c < 4; c++) {
                const uint4 w = wl[(d * 4 + c) * 512 + tid];
                const uint4 hb = hv4[c];
                s = fdot2f(bch2(w.x), bch2(hb.x), s);
                s = fdot2f(bch2(w.y), bch2(hb.y), s);
                s = fdot2f(bch2(w.z), bch2(hb.z), s);
                s = fdot2f(bch2(w.w), bch2(hb.w), s);
            }
            s += __shfl_xor(s, 1);                  // reduce 4 col-quarters
            s += __shfl_xor(s, 2);
            if (k < 3) {
                if (sub == 0) {
                    float* dst = &part[((t * 4 + d) * 4 + g) * 128 + rr];
                    *dst = s;                       // fast path: dirty local XCD L2
                    astore(dst, s);                 // fallback path: MALL (same value)
                }
            } else own = s;
        }

        if (sub == 0 && rr < myLen) {
            const int g1 = (g + 1) & 3, g2 = (g + 2) & 3, g3 = (g + 3) & 3;
            const float* pb = &part[(t * 4 + g) * 4 * 128];
            const float* p1 = &pb[g1 * 128 + rr];
            const float* p2 = &pb[g2 * 128 + rr];
            const float* p3 = &pb[g3 * 128 + rr];
            unsigned b1 = SENT, b2 = SENT, b3 = SENT;
            if (!fb) {
                int spins = 0;
                for (;;) {
                    l2load3(p1, p2, p3, b1, b2, b3);
                    if (b1 != SENT && b2 != SENT && b3 != SENT) break;
                    if (++spins >= SPINL) { fb = true; break; }
                }
            }
            if (b1 == SENT || b2 == SENT || b3 == SENT) {   // agent fallback
                do {
                    if (b1 == SENT) b1 = aload(p1);
                    if (b2 == SENT) b2 = aload(p2);
                    if (b3 == SENT) b3 = aload(p3);
                } while (b1 == SENT || b2 == SENT || b3 == SENT);
            }
            const float tot = own + __builtin_bit_cast(float, b1)
                                  + __builtin_bit_cast(float, b2)
                                  + __builtin_bit_cast(float, b3) + xp;
            const float hv = tanh_fast(tot);
            Hs[t * 512 + 128 * g + rr] = hv;        // plain; k2->k3 boundary flushes
            hch[cur ^ 1][rr] = (_Float16)hv;        // pads (rr>=myLen) stay 0
        }
        __syncthreads();
    }
}

// ---------------- K3: out[t][o] = tanh(b_out[o] + sum_c Hs[t][c]*W_out[o][c])
__global__ void k3_out(const float* __restrict__ Hs, const float* __restrict__ W_out,
                       const float* __restrict__ b_out, float* __restrict__ out) {
    const int t = blockIdx.x, o = threadIdx.x;
    if (o < D_OUT) {
        const float4* wr = (const float4*)(W_out + o * H);
        const float4* hr = (const float4*)(Hs + t * 512);
        float acc = b_out[o];
#pragma unroll 5
        for (int i = 0; i < 125; i++) {
            const float4 wv = wr[i];
            const float4 hv = hr[i];
            acc = fmaf(wv.x, hv.x, acc);
            acc = fmaf(wv.y, hv.y, acc);
            acc = fmaf(wv.z, hv.z, acc);
            acc = fmaf(wv.w, hv.w, acc);
        }
        out[t * D_OUT + o] = tanh_fast(acc);
    }
}

extern "C" void kernel_launch(void* const* d_in, const int* in_sizes, int n_in,
                              void* d_out, int out_size, void* d_ws, size_t ws_size,
                              hipStream_t stream) {
    const float* x       = (const float*)d_in[0];
    const float* hidden0 = (const float*)d_in[1];
    const float* W_ih    = (const float*)d_in[2];
    const float* W_hh    = (const float*)d_in[3];
    const float* b_ih    = (const float*)d_in[4];
    const float* b_hh    = (const float*)d_in[5];
    const float* W_out   = (const float*)d_in[6];
    const float* b_out   = (const float*)d_in[7];
    float* out = (float*)d_out;

    char* ws = (char*)d_ws;
    float*    part  = (float*)ws;                  // 49*4*4*128*4 = 401408 (sentinel)
    float*    xproj = (float*)(ws + 401408);       // 100352
    float*    Hs    = (float*)(ws + 501760);       // 100352
    unsigned* elect = (unsigned*)(ws + 602112);    // 64 B (cleared by k1 block 63)

    k1_xproj<<<88, 512, 0, stream>>>(x, W_ih, b_ih, b_hh, xproj, part, elect);
    k2_scan<<<NBLK2, 512, 0, stream>>>(hidden0, W_hh, xproj, part, Hs, elect);
    k3_out<<<STEPS, 128, 0, stream>>>(Hs, W_out, b_out, out);
}